// Round 15
// baseline (291.566 us; speedup 1.0000x reference)
//
#include <hip/hip_runtime.h>
#include <hip/hip_bf16.h>

// Supervised contrastive loss, B=8192, D=256, T=0.07, 100 classes.
//   memset: zero sn + cls_cnt + gacc + done (~34KB)
//   prep:   z f32 -> bf16 FRAGMENT-MAJOR zbf2 (1KB per (16-row-tile,kf)
//           fragment unit) + fused class bucketing.
//   passA:  row sums of exp(z@z^T/T), diagonal INCLUDED (cancels bitwise in
//           passB: same bf16 frags, same kf order -> identical e_ii).
//           Barrier-free, no LDS. 512 blocks = 16 row-blocks(512 rows) x
//           32 col-chunks(256 cols); 8 waves x 64 rows (a[4][8] = 128 VGPR).
//           All waves stream the SAME 16 B-tiles (L1 reuse, L2 B-traffic /8).
//           Software-pipelined: tile t+1's MFMAs issue before tile t's exp
//           epilogue (accA/accB double-buffer) so VALU runs under MFMA.
//           Fire-and-forget row atomics into sn.
//   passB:  per class (100 blocks x 8 waves): async-gather to LDS; pass1
//           per-mi loops (a-reuse), MFMA diag INCLUDED -> sums + e-cache in
//           dmat; sum_neg = sn - sums; pass2 log1p from dmat (no MFMA);
//           atomics into gacc; last block (done counter) writes out[0].

#define BN 8192
#define DD 256
#define INV_T (1.0f / 0.07f)
#define CAPI 256
#define CAP 160
#define IPAD 164

typedef __attribute__((ext_vector_type(8))) __bf16 bf16x8;
typedef __attribute__((ext_vector_type(4))) float f32x4;

typedef const __attribute__((address_space(1))) void gas_void;
typedef __attribute__((address_space(3))) void las_void;

static __device__ __forceinline__ void gld_lds16(const void* g, void* l) {
    __builtin_amdgcn_global_load_lds((gas_void*)g, (las_void*)l, 16, 0, 0);
}

static __device__ __forceinline__ unsigned short f2bf(float f) {
    unsigned int u = __builtin_bit_cast(unsigned int, f);
    u = (u + 0x7FFFu + ((u >> 16) & 1u)) >> 16;   // RNE, inputs finite
    return (unsigned short)u;
}
static __device__ __forceinline__ float bf2f(unsigned short s) {
    unsigned int u = (unsigned int)s << 16;
    return __builtin_bit_cast(float, u);
}

// ------- kernel 1: f32 -> bf16 fragment-major zbf2 + class bucketing ------
__global__ __launch_bounds__(256) void k_prep(const float* __restrict__ z,
                                              unsigned short* __restrict__ zbf2,
                                              const int* __restrict__ labels,
                                              int* __restrict__ cls_cnt,
                                              int* __restrict__ cls_idx) {
    const int gid = blockIdx.x * 256 + threadIdx.x;       // 262144 threads
    const float4* z4 = (const float4*)z;
    float4 v0 = z4[gid * 2 + 0];
    float4 v1 = z4[gid * 2 + 1];
    unsigned short r[8];
    r[0] = f2bf(v0.x); r[1] = f2bf(v0.y); r[2] = f2bf(v0.z); r[3] = f2bf(v0.w);
    r[4] = f2bf(v1.x); r[5] = f2bf(v1.y); r[6] = f2bf(v1.z); r[7] = f2bf(v1.w);
    const int j = gid >> 5, c5 = gid & 31;
    const int idx16 = (((j >> 4) * 8 + (c5 >> 2)) * 64) + (c5 & 3) * 16 + (j & 15);
    ((uint4*)zbf2)[idx16] = *(const uint4*)r;
    if (gid < BN) {                                       // cls_cnt pre-zeroed
        const int c = labels[gid];
        const int slot = atomicAdd(&cls_cnt[c], 1);
        if (slot < CAPI) cls_idx[c * CAPI + slot] = gid;
    }
}

// ---------------- kernel 2: row sums of exp(z z^T / T), diag included -----
// Grid 512 = 16 row-blocks x 32 col-chunks. 512 thr = 8 waves x 64 rows.
// All waves stream the same 16 col-tiles (L1 reuse). Pipelined epilogue.
__global__ __launch_bounds__(512, 2) void k_passA(const char* __restrict__ zb2,
                                                  float* __restrict__ sn) {
    const int tid = threadIdx.x;
    const int w = tid >> 6, lane = tid & 63;
    const int l15 = lane & 15, lk = lane >> 4;
    const int rowbase = (blockIdx.x >> 5) * 512 + w * 64;
    const int jt0 = (blockIdx.x & 31) * 16;   // 16 shared col-tiles

    // A: this wave's 64 rows, full K (fragment-major; one dwordx4 per frag)
    const int rt0 = rowbase >> 4;
    bf16x8 a[4][8];
#pragma unroll
    for (int m = 0; m < 4; ++m) {
        const char* p = zb2 + ((size_t)(rt0 + m) * 8192) + lane * 16;
#pragma unroll
        for (int kf = 0; kf < 8; ++kf)
            a[m][kf] = *(const bf16x8*)(p + kf * 1024);
    }

    float snp[4][4] = {};
    bf16x8 b0[8], b1[8];
    f32x4 accA[4], accB[4];

    auto loadB0 = [&](int jt) {
        const char* p = zb2 + ((size_t)jt * 8192) + lane * 16;
#pragma unroll
        for (int kf = 0; kf < 8; ++kf) b0[kf] = *(const bf16x8*)(p + kf * 1024);
    };
    auto loadB1 = [&](int jt) {
        const char* p = zb2 + ((size_t)jt * 8192) + lane * 16;
#pragma unroll
        for (int kf = 0; kf < 8; ++kf) b1[kf] = *(const bf16x8*)(p + kf * 1024);
    };
    auto mfmaT = [&](f32x4 (&acc)[4], bf16x8 (&bx)[8]) {
#pragma unroll
        for (int m = 0; m < 4; ++m) acc[m] = (f32x4){0.f, 0.f, 0.f, 0.f};
#pragma unroll
        for (int kf = 0; kf < 8; ++kf)
#pragma unroll
            for (int m = 0; m < 4; ++m)
                acc[m] = __builtin_amdgcn_mfma_f32_16x16x32_bf16(a[m][kf], bx[kf], acc[m], 0, 0, 0);
    };
    auto epi = [&](f32x4 (&acc)[4]) {        // no diag mask (cancels in passB)
#pragma unroll
        for (int m = 0; m < 4; ++m)
#pragma unroll
            for (int rr = 0; rr < 4; ++rr)
                snp[m][rr] += __expf(acc[m][rr] * INV_T);
    };

    loadB0(jt0);
    loadB1(jt0 + 1);
    mfmaT(accA, b0);                          // tile 0
#pragma unroll
    for (int t = 1; t < 15; t += 2) {
        loadB0(jt0 + t + 1);
        mfmaT(accB, b1);                      // tile t   (MFMA issues first)
        epi(accA);                            // tile t-1 (VALU under MFMA)
        loadB1(jt0 + t + 2);
        mfmaT(accA, b0);                      // tile t+1
        epi(accB);                            // tile t
    }
    mfmaT(accB, b1);                          // tile 15
    epi(accA);                                // tile 14
    epi(accB);                                // tile 15

    // reduce across the 16 l15 lanes sharing each row; one atomic per row
#pragma unroll
    for (int m = 0; m < 4; ++m) {
#pragma unroll
        for (int rr = 0; rr < 4; ++rr) {
            float v = snp[m][rr];
            v += __shfl_xor(v, 1, 64);
            v += __shfl_xor(v, 2, 64);
            v += __shfl_xor(v, 4, 64);
            v += __shfl_xor(v, 8, 64);
            if (l15 == 0)
                atomicAdd(&sn[rowbase + m * 16 + lk * 4 + rr], v);
        }
    }
}

// ---------------- kernel 3: per-class positive pairs + final --------------
// 100 blocks x 512 thr (8 waves). Per-mi loops (a-reuse), e-cache in dmat.
__global__ __launch_bounds__(512) void k_passB(const unsigned short* __restrict__ zbf2_unused,
                                               const float* __restrict__ zf,
                                               const float* __restrict__ sn,
                                               const int* __restrict__ cls_cnt,
                                               const int* __restrict__ cls_idx,
                                               float* __restrict__ gacc,
                                               int* __restrict__ done,
                                               float* __restrict__ out) {
    __shared__ char Zc[CAP * 512];             // swizzled [row][512 B]
    __shared__ unsigned short dmat[CAP * IPAD];// col-major e cache [j][iPad]
    __shared__ int glist[CAP];
    __shared__ float sums[CAP];
    __shared__ float snl[CAP];
    __shared__ float blkL;

    const int c = blockIdx.x;
    const int tid = threadIdx.x;
    const int w = tid >> 6, lane = tid & 63;
    const int l15 = lane & 15, lk = lane >> 4;

    const int n_c = min(cls_cnt[c], CAP);
    const int nt = (n_c + 15) >> 4;
    const int rows_p = nt * 16;

    if (tid < CAP) glist[tid] = (tid < n_c) ? cls_idx[c * CAPI + tid] : 0;
    if (tid == 0) blkL = 0.f;
    __syncthreads();

    // gather: 32 lanes per row; read f32, convert (bitwise == zbf2 bits)
    for (int e2 = w * 2; e2 < rows_p; e2 += 16) {
        const int row = e2 + (lane >> 5);
        const int li = lane & 31;
        const float* src = zf + (size_t)glist[row] * DD + li * 8;
        float4 v0 = *(const float4*)(src);
        float4 v1 = *(const float4*)(src + 4);
        unsigned short r[8];
        r[0] = f2bf(v0.x); r[1] = f2bf(v0.y); r[2] = f2bf(v0.z); r[3] = f2bf(v0.w);
        r[4] = f2bf(v1.x); r[5] = f2bf(v1.y); r[6] = f2bf(v1.z); r[7] = f2bf(v1.w);
        *(uint4*)(Zc + row * 512 + ((li * 16) ^ ((row & 7) << 4))) = *(const uint4*)r;
    }
    __syncthreads();

    // ---- pass 1: sum_same (diag INCLUDED -> cancels passA's diag) ----
    for (int mi = w; mi < nt; mi += 8) {
        const int rowA = mi * 16 + l15;
        const int swa = (rowA & 7) << 4;
        bf16x8 a[8];
#pragma unroll
        for (int kf = 0; kf < 8; ++kf)
            a[kf] = *(const bf16x8*)(Zc + rowA * 512 + ((lk * 16 + kf * 64) ^ swa));
        float sp[4] = {};
        for (int nj = 0; nj < nt; ++nj) {
            const int colB = nj * 16 + l15;
            const int swb = (colB & 7) << 4;
            bf16x8 b[8];
#pragma unroll
            for (int kf = 0; kf < 8; ++kf)
                b[kf] = *(const bf16x8*)(Zc + colB * 512 + ((lk * 16 + kf * 64) ^ swb));
            f32x4 acc = {};
#pragma unroll
            for (int kf = 0; kf < 8; ++kf)
                acc = __builtin_amdgcn_mfma_f32_16x16x32_bf16(a[kf], b[kf], acc, 0, 0, 0);
            unsigned short ep[4];
#pragma unroll
            for (int rr = 0; rr < 4; ++rr) {
                const float e = __expf(acc[rr] * INV_T);
                ep[rr] = f2bf(e);
                sp[rr] += (colB < n_c) ? e : 0.f;         // diag included
            }
            uint2 uv;
            uv.x = (unsigned)ep[0] | ((unsigned)ep[1] << 16);
            uv.y = (unsigned)ep[2] | ((unsigned)ep[3] << 16);
            *(uint2*)&dmat[colB * IPAD + mi * 16 + lk * 4] = uv;
        }
#pragma unroll
        for (int rr = 0; rr < 4; ++rr) {
            float v = sp[rr];
            v += __shfl_xor(v, 1, 64);
            v += __shfl_xor(v, 2, 64);
            v += __shfl_xor(v, 4, 64);
            v += __shfl_xor(v, 8, 64);
            if (l15 == 0) sums[mi * 16 + lk * 4 + rr] = v;
        }
    }
    __syncthreads();
    if (tid < CAP)
        snl[tid] = (tid < n_c) ? (sn[glist[tid]] - sums[tid]) : 0.f;
    __syncthreads();

    // ---- pass 2: pair losses from the e-cache (no MFMA) ----
    for (int mi = w; mi < nt; mi += 8) {
        float sneg[4];
#pragma unroll
        for (int rr = 0; rr < 4; ++rr) {
            const int i = mi * 16 + lk * 4 + rr;
            sneg[rr] = (i < n_c) ? snl[i] : 0.f;
        }
        float sp[4] = {};
        for (int nj = 0; nj < nt; ++nj) {
            const int colB = nj * 16 + l15;
            const uint2 pk = *(const uint2*)&dmat[colB * IPAD + mi * 16 + lk * 4];
            float ev[4];
            ev[0] = bf2f((unsigned short)(pk.x & 0xffff));
            ev[1] = bf2f((unsigned short)(pk.x >> 16));
            ev[2] = bf2f((unsigned short)(pk.y & 0xffff));
            ev[3] = bf2f((unsigned short)(pk.y >> 16));
#pragma unroll
            for (int rr = 0; rr < 4; ++rr) {
                const int i = mi * 16 + lk * 4 + rr;
                const float t = log1pf(sneg[rr] / ev[rr]);
                sp[rr] += (colB < n_c && i != colB) ? t : 0.f;
            }
        }
#pragma unroll
        for (int rr = 0; rr < 4; ++rr) {
            float v = sp[rr];
            v += __shfl_xor(v, 1, 64);
            v += __shfl_xor(v, 2, 64);
            v += __shfl_xor(v, 4, 64);
            v += __shfl_xor(v, 8, 64);
            const int i = mi * 16 + lk * 4 + rr;
            if (l15 == 0 && i < n_c && n_c > 1)
                atomicAdd(&blkL, v / (float)(n_c - 1));
        }
    }
    __syncthreads();

    if (tid == 0) {
        if (n_c > 1) {
            atomicAdd(&gacc[0], blkL);
            atomicAdd(&gacc[1], (float)n_c);
        }
        __threadfence();
        const int old = atomicAdd(done, 1);
        if (old == 99) {                       // last block finalizes
            const float L = atomicAdd(&gacc[0], 0.f);
            const float V = atomicAdd(&gacc[1], 0.f);
            out[0] = (V > 0.f) ? L / fmaxf(V, 1.f) : 0.f;
        }
    }
}

extern "C" void kernel_launch(void* const* d_in, const int* in_sizes, int n_in,
                              void* d_out, int out_size, void* d_ws, size_t ws_size,
                              hipStream_t stream) {
    const float* z      = (const float*)d_in[0];
    const int*   labels = (const int*)d_in[1];
    float* out = (float*)d_out;

    char* ws = (char*)d_ws;
    // zbf2 4MB | [sn 32KB | cls_cnt 1KB | gacc 8B | done 4B | pad] (memset)
    // | cls_idx 100KB
    unsigned short* zbf2 = (unsigned short*)ws;
    size_t off = (size_t)BN * DD * sizeof(unsigned short);
    char*  mz      = ws + off;
    float* sn      = (float*)(ws + off);  off += BN * sizeof(float);
    int*   cls_cnt = (int*)(ws + off);    off += 1024;
    float* gacc    = (float*)(ws + off);  off += 8;
    int*   done    = (int*)(ws + off);    off += 4;
    off += 244;
    size_t mz_bytes = (size_t)((ws + off) - mz);
    int*   cls_idx = (int*)(ws + off);    off += 100 * CAPI * sizeof(int);

    hipMemsetAsync(mz, 0, mz_bytes, stream);
    k_prep  <<<1024, 256, 0, stream>>>(z, zbf2, labels, cls_cnt, cls_idx);
    k_passA <<<512, 512, 0, stream>>>((const char*)zbf2, sn);
    k_passB <<<100, 512, 0, stream>>>((const unsigned short*)zbf2, z, sn,
                                      cls_cnt, cls_idx, gacc, done, out);
}

// Round 16
// 78.155 us; speedup vs baseline: 3.7306x; 3.7306x over previous
//
#include <hip/hip_runtime.h>
#include <hip/hip_bf16.h>

// Supervised contrastive loss, B=8192, D=256, T=0.07, 100 classes.
//   memset: zero cls_cnt + gacc + done (1280 B)
//   prep:   z f32 -> bf16 row-major zbf + fused class bucketing
//   passA:  row sums of exp(z@z^T/T), diag masked (R8 structure, measured
//           43.5us x3 reproductions): 256 blocks = 64 row-tiles x 4
//           col-quarters, 8 waves (2 wr x 4 wc, m=4), A regs via LDS bounce,
//           128-col dbuf LDS staging via global_load_lds w16 + XOR swizzle.
//           Per-block sn_part stores (no atomics).
//   passB:  per class (100 blocks x 8 waves), single kernel: async-gather
//           members to LDS; pass1 PER-MI loops (a[8] loaded once per row-
//           tile, sp in regs over nj) -> sums + e-cache in LDS dmat;
//           sum_neg = sum_all - sum_same; pass2 = log1p from dmat (no
//           second MFMA); atomics into gacc; last block (done counter)
//           writes out[0]. No k_bucket / k_final dispatches.

#define BN 8192
#define DD 256
#define INV_T (1.0f / 0.07f)
#define CAPI 256
#define CAP 160
#define IPAD 164

typedef __attribute__((ext_vector_type(8))) __bf16 bf16x8;
typedef __attribute__((ext_vector_type(4))) float f32x4;

typedef const __attribute__((address_space(1))) void gas_void;
typedef __attribute__((address_space(3))) void las_void;

static __device__ __forceinline__ void gld_lds16(const void* g, void* l) {
    __builtin_amdgcn_global_load_lds((gas_void*)g, (las_void*)l, 16, 0, 0);
}

static __device__ __forceinline__ unsigned short f2bf(float f) {
    unsigned int u = __builtin_bit_cast(unsigned int, f);
    u = (u + 0x7FFFu + ((u >> 16) & 1u)) >> 16;   // RNE, inputs finite
    return (unsigned short)u;
}
static __device__ __forceinline__ float bf2f(unsigned short s) {
    unsigned int u = (unsigned int)s << 16;
    return __builtin_bit_cast(float, u);
}

// ------- kernel 1: f32 -> bf16 row-major zbf + fused class bucketing ------
__global__ __launch_bounds__(256) void k_prep(const float* __restrict__ z,
                                              unsigned short* __restrict__ zbf,
                                              const int* __restrict__ labels,
                                              int* __restrict__ cls_cnt,
                                              int* __restrict__ cls_idx) {
    const int gid = blockIdx.x * 256 + threadIdx.x;       // 262144 threads
    const float4* z4 = (const float4*)z;
    float4 v0 = z4[gid * 2 + 0];
    float4 v1 = z4[gid * 2 + 1];
    unsigned short r[8];
    r[0] = f2bf(v0.x); r[1] = f2bf(v0.y); r[2] = f2bf(v0.z); r[3] = f2bf(v0.w);
    r[4] = f2bf(v1.x); r[5] = f2bf(v1.y); r[6] = f2bf(v1.z); r[7] = f2bf(v1.w);
    ((uint4*)zbf)[gid] = *(const uint4*)r;
    if (gid < BN) {                                       // cls_cnt pre-zeroed
        const int c = labels[gid];
        const int slot = atomicAdd(&cls_cnt[c], 1);
        if (slot < CAPI) cls_idx[c * CAPI + slot] = gid;
    }
}

// ---------------- kernel 2: row sums of exp(z z^T / T), diag masked -------
// Grid 256 = 64 row-tiles x 4 col-quarters. 512 thr = 8 waves (2 wr x 4 wc).
// Block: 128 rows x 2048 cols; per step 128 cols staged in LDS (dbuf).
__global__ __launch_bounds__(512, 2) void k_passA(const unsigned short* __restrict__ zbf,
                                                  float* __restrict__ sn_part) {
    __shared__ char Bb[2][65536];             // [128 cols][512 B], swizzled
    __shared__ float sn_lds[128];

    const int tid = threadIdx.x;
    const int by = blockIdx.x >> 2;
    const int cq = blockIdx.x & 3;
    const int rowbase = by * 128;
    const int colbase = cq * 2048;
    const char* zb = (const char*)zbf;

    auto stage = [&](int buf, int ns) {       // 128 cols x 512 B, swizzled
        const char* gB = zb + ((size_t)(colbase + ns * 128)) * 512;
        char* lb = Bb[buf];
#pragma unroll
        for (int qq = 0; qq < 8; ++qq) {
            const int s = (qq * 512 + tid) * 16;
            const int col = s >> 9, koff = s & 511;
            const int ksrc = koff ^ ((col & 7) << 4);   // pre-swizzled source
            gld_lds16(gB + (size_t)col * 512 + ksrc, lb + s);
        }
    };

    const int w = tid >> 6, lane = tid & 63;
    const int l15 = lane & 15, lk = lane >> 4;
    const int wr = w & 1, wc = w >> 1;        // 2 row-groups x 4 col-groups

    // ---- A tile via LDS bounce: stage rows once, read frags to regs ----
    {
        const char* gA = zb + (size_t)rowbase * 512;
        char* lb = Bb[0];
#pragma unroll
        for (int qq = 0; qq < 8; ++qq) {
            const int s = (qq * 512 + tid) * 16;
            const int row = s >> 9, koff = s & 511;
            const int ksrc = koff ^ ((row & 7) << 4);
            gld_lds16(gA + (size_t)row * 512 + ksrc, lb + s);
        }
    }
    __syncthreads();                          // A staged (barrier drains vmcnt)

    bf16x8 a[4][8];
#pragma unroll
    for (int m = 0; m < 4; ++m) {
        const int row = wr * 64 + m * 16 + l15;
        const int sw = (row & 7) << 4;
#pragma unroll
        for (int kf = 0; kf < 8; ++kf)
            a[m][kf] = *(const bf16x8*)(Bb[0] + row * 512 + ((lk * 16 + kf * 64) ^ sw));
    }
    int iglob[4][4];
#pragma unroll
    for (int m = 0; m < 4; ++m)
#pragma unroll
        for (int rr = 0; rr < 4; ++rr)
            iglob[m][rr] = rowbase + wr * 64 + m * 16 + lk * 4 + rr;

    if (tid < 128) sn_lds[tid] = 0.f;
    float snp[4][4] = {};

    __syncthreads();                          // A-frag reads complete
    stage(0, 0);
    __syncthreads();                          // buf0 ready

    for (int ns = 0; ns < 16; ++ns) {
        const int buf = ns & 1;
        if (ns < 15) stage(buf ^ 1, ns + 1);
        const char* bp0 = Bb[buf];
#pragma unroll
        for (int n = 0; n < 2; ++n) {
            const int colL = wc * 32 + n * 16 + l15;
            const char* bp = bp0 + (size_t)colL * 512;
            const int sw = (colL & 7) << 4;
            bf16x8 b[8];
#pragma unroll
            for (int kf = 0; kf < 8; ++kf)
                b[kf] = *(const bf16x8*)(bp + ((lk * 16 + kf * 64) ^ sw));
            const int jj = colbase + ns * 128 + colL;
#pragma unroll
            for (int m = 0; m < 4; ++m) {
                f32x4 acc = {};
#pragma unroll
                for (int kf = 0; kf < 8; ++kf)
                    acc = __builtin_amdgcn_mfma_f32_16x16x32_bf16(a[m][kf], b[kf], acc, 0, 0, 0);
#pragma unroll
                for (int rr = 0; rr < 4; ++rr) {
                    float e = __expf(acc[rr] * INV_T);
                    if (iglob[m][rr] == jj) e = 0.f;     // mask diagonal
                    snp[m][rr] += e;
                }
            }
        }
        __syncthreads();
    }

    // reduce across the 16 l15 lanes sharing each row, combine wc-groups in LDS
#pragma unroll
    for (int m = 0; m < 4; ++m) {
#pragma unroll
        for (int rr = 0; rr < 4; ++rr) {
            float v = snp[m][rr];
            v += __shfl_xor(v, 1, 64);
            v += __shfl_xor(v, 2, 64);
            v += __shfl_xor(v, 4, 64);
            v += __shfl_xor(v, 8, 64);
            if (l15 == 0)
                atomicAdd(&sn_lds[wr * 64 + m * 16 + lk * 4 + rr], v);
        }
    }
    __syncthreads();
    if (tid < 128)
        sn_part[(size_t)cq * BN + rowbase + tid] = sn_lds[tid];
}

// ---------------- kernel 3: per-class positive pairs + final --------------
// 100 blocks x 512 thr (8 waves). Per-mi loops (a-reuse), e-cache in dmat;
// last block (done counter) writes out[0].
__global__ __launch_bounds__(512) void k_passB(const unsigned short* __restrict__ zbf,
                                               const float* __restrict__ sn_part,
                                               const int* __restrict__ cls_cnt,
                                               const int* __restrict__ cls_idx,
                                               float* __restrict__ gacc,
                                               int* __restrict__ done,
                                               float* __restrict__ out) {
    __shared__ char Zc[CAP * 512];             // swizzled [row][512 B]
    __shared__ unsigned short dmat[CAP * IPAD];// col-major e cache [j][iPad]
    __shared__ int glist[CAP];
    __shared__ float sums[CAP];
    __shared__ float snl[CAP];
    __shared__ float blkL;

    const int c = blockIdx.x;
    const int tid = threadIdx.x;
    const int w = tid >> 6, lane = tid & 63;
    const int l15 = lane & 15, lk = lane >> 4;
    const char* zb = (const char*)zbf;

    const int n_c = min(cls_cnt[c], CAP);
    const int nt = (n_c + 15) >> 4;
    const int rows_p = nt * 16;

    if (tid < CAP) glist[tid] = (tid < n_c) ? cls_idx[c * CAPI + tid] : 0;
    if (tid == 0) blkL = 0.f;
    __syncthreads();

    // async gather: one wave-instr moves 2 rows (64 lanes x 16B), swizzled src
    for (int e2 = w * 2; e2 < rows_p; e2 += 16) {
        const int row = e2 + (lane >> 5);
        const int cb = (lane & 31) * 16;
        gld_lds16(zb + (size_t)glist[row] * 512 + (cb ^ ((row & 7) << 4)),
                  (char*)Zc + e2 * 512);
    }
    __syncthreads();                           // vmcnt drained by barrier

    // ---- pass 1: sum_same + e-cache (per-mi loops, a-reuse) ----
    for (int mi = w; mi < nt; mi += 8) {
        const int rowA = mi * 16 + l15;
        const int swa = (rowA & 7) << 4;
        bf16x8 a[8];
#pragma unroll
        for (int kf = 0; kf < 8; ++kf)
            a[kf] = *(const bf16x8*)(Zc + rowA * 512 + ((lk * 16 + kf * 64) ^ swa));
        float sp[4] = {};
        for (int nj = 0; nj < nt; ++nj) {
            const int colB = nj * 16 + l15;
            const int swb = (colB & 7) << 4;
            bf16x8 b[8];
#pragma unroll
            for (int kf = 0; kf < 8; ++kf)
                b[kf] = *(const bf16x8*)(Zc + colB * 512 + ((lk * 16 + kf * 64) ^ swb));
            f32x4 acc = {};
#pragma unroll
            for (int kf = 0; kf < 8; ++kf)
                acc = __builtin_amdgcn_mfma_f32_16x16x32_bf16(a[kf], b[kf], acc, 0, 0, 0);
            unsigned short ep[4];
#pragma unroll
            for (int rr = 0; rr < 4; ++rr) {
                const int i = mi * 16 + lk * 4 + rr;
                const float e = __expf(acc[rr] * INV_T);
                ep[rr] = f2bf(e);
                sp[rr] += (colB < n_c && i != colB) ? e : 0.f;
            }
            uint2 uv;
            uv.x = (unsigned)ep[0] | ((unsigned)ep[1] << 16);
            uv.y = (unsigned)ep[2] | ((unsigned)ep[3] << 16);
            *(uint2*)&dmat[colB * IPAD + mi * 16 + lk * 4] = uv;
        }
#pragma unroll
        for (int rr = 0; rr < 4; ++rr) {
            float v = sp[rr];
            v += __shfl_xor(v, 1, 64);
            v += __shfl_xor(v, 2, 64);
            v += __shfl_xor(v, 4, 64);
            v += __shfl_xor(v, 8, 64);
            if (l15 == 0) sums[mi * 16 + lk * 4 + rr] = v;
        }
    }
    __syncthreads();
    if (tid < CAP) {
        float v = 0.f;
        if (tid < n_c) {
            const int g = glist[tid];
            v = sn_part[g] + sn_part[BN + g] + sn_part[2 * BN + g]
              + sn_part[3 * BN + g] - sums[tid];
        }
        snl[tid] = v;
    }
    __syncthreads();

    // ---- pass 2: pair losses from the e-cache (no MFMA) ----
    for (int mi = w; mi < nt; mi += 8) {
        float sneg[4];
#pragma unroll
        for (int rr = 0; rr < 4; ++rr) {
            const int i = mi * 16 + lk * 4 + rr;
            sneg[rr] = (i < n_c) ? snl[i] : 0.f;
        }
        float sp[4] = {};
        for (int nj = 0; nj < nt; ++nj) {
            const int colB = nj * 16 + l15;
            const uint2 pk = *(const uint2*)&dmat[colB * IPAD + mi * 16 + lk * 4];
            float ev[4];
            ev[0] = bf2f((unsigned short)(pk.x & 0xffff));
            ev[1] = bf2f((unsigned short)(pk.x >> 16));
            ev[2] = bf2f((unsigned short)(pk.y & 0xffff));
            ev[3] = bf2f((unsigned short)(pk.y >> 16));
#pragma unroll
            for (int rr = 0; rr < 4; ++rr) {
                const int i = mi * 16 + lk * 4 + rr;
                const float t = log1pf(sneg[rr] / ev[rr]);
                sp[rr] += (colB < n_c && i != colB) ? t : 0.f;
            }
        }
#pragma unroll
        for (int rr = 0; rr < 4; ++rr) {
            float v = sp[rr];
            v += __shfl_xor(v, 1, 64);
            v += __shfl_xor(v, 2, 64);
            v += __shfl_xor(v, 4, 64);
            v += __shfl_xor(v, 8, 64);
            const int i = mi * 16 + lk * 4 + rr;
            if (l15 == 0 && i < n_c && n_c > 1)
                atomicAdd(&blkL, v / (float)(n_c - 1));
        }
    }
    __syncthreads();

    if (tid == 0) {
        if (n_c > 1) {
            atomicAdd(&gacc[0], blkL);
            atomicAdd(&gacc[1], (float)n_c);
        }
        __threadfence();
        const int old = atomicAdd(done, 1);
        if (old == 99) {                       // last block finalizes
            const float L = atomicAdd(&gacc[0], 0.f);
            const float V = atomicAdd(&gacc[1], 0.f);
            out[0] = (V > 0.f) ? L / fmaxf(V, 1.f) : 0.f;
        }
    }
}

extern "C" void kernel_launch(void* const* d_in, const int* in_sizes, int n_in,
                              void* d_out, int out_size, void* d_ws, size_t ws_size,
                              hipStream_t stream) {
    const float* z      = (const float*)d_in[0];
    const int*   labels = (const int*)d_in[1];
    float* out = (float*)d_out;

    char* ws = (char*)d_ws;
    // zbf 4MB | sn_part 4xBN f32 | [cls_cnt 1KB | gacc 8B | done 4B | pad]
    // (memset 1280B) | cls_idx 100KB
    unsigned short* zbf = (unsigned short*)ws;
    size_t off = (size_t)BN * DD * sizeof(unsigned short);
    float* sn_part = (float*)(ws + off);  off += 4 * BN * sizeof(float);
    char*  mz      = ws + off;
    int*   cls_cnt = (int*)(ws + off);    off += 1024;
    float* gacc    = (float*)(ws + off);  off += 8;
    int*   done    = (int*)(ws + off);    off += 4;
    off += 244;                                           // pad to 1280
    int*   cls_idx = (int*)(ws + off);    off += 100 * CAPI * sizeof(int);

    hipMemsetAsync(mz, 0, 1280, stream);
    k_prep  <<<1024, 256, 0, stream>>>(z, zbf, labels, cls_cnt, cls_idx);
    k_passA <<<256, 512, 0, stream>>>(zbf, sn_part);
    k_passB <<<100, 512, 0, stream>>>(zbf, sn_part, cls_cnt, cls_idx, gacc, done, out);
}